// Round 11
// baseline (415.257 us; speedup 1.0000x reference)
//
#include <hip/hip_runtime.h>

typedef unsigned int u32;
typedef unsigned short u16;
typedef __attribute__((ext_vector_type(8))) short short8;   // 8 x bf16 (guide-verified frag type)
typedef __attribute__((ext_vector_type(4))) float f32x4;

#define POOLCAP 65536
#define IDXMASK 0x1ffff   // src index lives in bits 0..16; deg in bits 17..31
#define BUCKCAP 12288     // fixed pairs segment per bucket (mean 8192, sigma~90 -> +45 sigma)

__device__ __forceinline__ u16 f2bf(float f) {
    u32 u = __float_as_uint(f);
    u32 r = (u + 0x7fffu + ((u >> 16) & 1u)) >> 16;   // RNE
    return (u16)r;
}
__device__ __forceinline__ float bf2f(u32 lo16) { return __uint_as_float(lo16 << 16); }

// packed accumulate: a[i] += {lo(w), hi(w)}
__device__ __forceinline__ void acc_u4p(float2* a, uint4 v) {
    u32 w[4] = {v.x, v.y, v.z, v.w};
#pragma unroll
    for (int i = 0; i < 4; i++) {
        a[i].x += __uint_as_float(w[i] << 16);
        a[i].y += __uint_as_float(w[i] & 0xffff0000u);
    }
}

// ---------------- LEAN scatter + weight-prep ----------------
// blocks [0, NS): scatter. blocks [NS, NS+160): transposed-weight prep.
#define TILE 4096
__global__ __launch_bounds__(512) void scatter_prep(const int* __restrict__ src,
                                                    const int* __restrict__ dst,
                                                    int* __restrict__ cursor,
                                                    uint2* __restrict__ pairs, int E, int NS,
                                                    const float* __restrict__ ws0, const float* __restrict__ wn0, u16* __restrict__ wt0,
                                                    const float* __restrict__ ws1, const float* __restrict__ wn1, u16* __restrict__ wt1,
                                                    const float* __restrict__ ws2, const float* __restrict__ wn2, u16* __restrict__ wt2) {
    if (blockIdx.x >= NS) {                            // ---- weight prep ----
        int local = blockIdx.x - NS;
        const float *ws, *wn;
        u16* wt;
        int dout, HW;
        if (local < 64)       { ws = ws0; wn = wn0; wt = wt0; dout = 128; HW = 128; }
        else if (local < 128) { ws = ws1; wn = wn1; wt = wt1; dout = 128; HW = 128; local -= 64; }
        else                  { ws = ws2; wn = wn2; wt = wt2; dout = 47;  HW = 64;  local -= 128; }
        int idx = local * 512 + threadIdx.x;           // idx = n*128 + k
        int n = idx >> 7, k = idx & 127;
        float v = 0.f;
        if (n < HW) { if (n < dout) v = ws[k * dout + n]; }
        else { int nn = n - HW; if (nn < dout) v = wn[k * dout + nn]; }
        wt[idx] = f2bf(v);
        return;
    }
    // ---- lean bucket scatter ----
    __shared__ int s_cnt[256];
    __shared__ int s_gpos[256];
    const int tid = threadIdx.x;
    const int base = blockIdx.x * TILE;
    const int tn = min(TILE, E - base);
    if (tid < 256) s_cnt[tid] = 0;
    __syncthreads();
    int d[8], s[8], r[8];
#pragma unroll
    for (int j = 0; j < 8; j++) {
        int k = tid + j * 512;
        if (k < tn) {
            d[j] = dst[base + k];
            s[j] = src[base + k];
            r[j] = atomicAdd(&s_cnt[d[j] >> 9], 1);    // rank = final within-block slot
        } else d[j] = -1;
    }
    __syncthreads();
    if (tid < 256 && s_cnt[tid] > 0) s_gpos[tid] = atomicAdd(&cursor[tid], s_cnt[tid]);
    __syncthreads();
#pragma unroll
    for (int j = 0; j < 8; j++) {
        if (d[j] >= 0) {
            int b = d[j] >> 9;
            int pos = s_gpos[b] + r[j];
            if (pos < BUCKCAP)                         // overflow guard (~0 probability)
                pairs[(size_t)b * BUCKCAP + pos] = make_uint2((u32)d[j], (u32)s[j]);
        }
    }
}

// ---------------- build: FIXED-STRIDE placement, single pass over pairs ----------------
__global__ __launch_bounds__(512) void build_csr3(const uint2* __restrict__ pairs,
                                                  const int* __restrict__ cursor,
                                                  float* __restrict__ invd,
                                                  int* __restrict__ colsF,
                                                  uint2* __restrict__ pool,
                                                  int* __restrict__ gcnt,
                                                  int Nn) {
    __shared__ int s_fix[512 * 32];                    // 64 KB fixed table
    __shared__ int s_cnt[512];
    const int tid = threadIdx.x;
    const int d0 = blockIdx.x * 512;
    const int nd = min(512, Nn - d0);
    const size_t base = (size_t)blockIdx.x * BUCKCAP;
    const int n = min(cursor[blockIdx.x], BUCKCAP);
    s_cnt[tid] = 0;
    __syncthreads();
    for (int k = tid; k < n; k += 512) {               // single read of pairs, direct place
        uint2 pr = pairs[base + k];
        int dl = (int)pr.x - d0;
        int p = atomicAdd(&s_cnt[dl], 1);
        if (p < 32) s_fix[dl * 32 + p] = (int)pr.y;
        else {
            int q = atomicAdd(gcnt, 1);
            if (q < POOLCAP) pool[q] = make_uint2(pr.x, pr.y);
        }
    }
    __syncthreads();
    if (tid < nd) invd[d0 + tid] = 1.0f / (float)max(s_cnt[tid], 1);
    // coalesced writeback; sentinels + deg tag synthesized on the fly
    int4* dst4 = (int4*)(colsF + (size_t)d0 * 32);
    for (int k = tid; k < 512 * 32 / 4; k += 512) {
        int node = k >> 3;                             // 8 int4 per node
        int cnt = s_cnt[node];
        int dg = min(cnt, 0x7fff) << 17;
        int sb = (k & 7) * 4;
        int4 v;
        v.x = ((sb + 0 < cnt) ? s_fix[k * 4 + 0] : Nn) | dg;
        v.y = ((sb + 1 < cnt) ? s_fix[k * 4 + 1] : Nn) | dg;
        v.z = ((sb + 2 < cnt) ? s_fix[k * 4 + 2] : Nn) | dg;
        v.w = ((sb + 3 < cnt) ? s_fix[k * 4 + 3] : Nn) | dg;
        dst4[k] = v;
    }
}

// ---------------- fused GEMM: C[M][NCOLS] = A[M][128] @ Bt^T  (fp32 acc) ----------------
#define KDIM 128
#define KP 136

template <int NCOLS, bool AF32>
__global__ __launch_bounds__(256) void gemm_bf16(const void* __restrict__ Ap,
                                                 const u16* __restrict__ Bt,
                                                 u16* __restrict__ C, int M) {
    __shared__ u16 As[64 * KP];
    __shared__ u16 Bs[128 * KP];
    const int row0 = blockIdx.x * 64;
    const int col0 = blockIdx.y * 128;
    const int tid = threadIdx.x;

#pragma unroll
    for (int i = 0; i < 4; i++) {
        int idx = tid + i * 256;
        int r = idx >> 4, c = idx & 15;
        uint4 v = make_uint4(0, 0, 0, 0);
        if (row0 + r < M) {
            if (AF32) {
                const float* Af = (const float*)Ap;
                const float4* rowp = (const float4*)(Af + (size_t)(row0 + r) * KDIM);
                float4 f0 = rowp[2 * c];
                float4 f1 = rowp[2 * c + 1];
                v.x = (u32)f2bf(f0.x) | ((u32)f2bf(f0.y) << 16);
                v.y = (u32)f2bf(f0.z) | ((u32)f2bf(f0.w) << 16);
                v.z = (u32)f2bf(f1.x) | ((u32)f2bf(f1.y) << 16);
                v.w = (u32)f2bf(f1.z) | ((u32)f2bf(f1.w) << 16);
            } else {
                const u16* Ab = (const u16*)Ap;
                v = ((const uint4*)(Ab + (size_t)(row0 + r) * KDIM))[c];
            }
        }
        ((uint4*)(As + r * KP))[c] = v;
    }
#pragma unroll
    for (int i = 0; i < 8; i++) {
        int idx = tid + i * 256;
        int r = idx >> 4, c = idx & 15;
        uint4 v = ((const uint4*)(Bt + (size_t)(col0 + r) * KDIM))[c];
        ((uint4*)(Bs + r * KP))[c] = v;
    }
    __syncthreads();

    const int lane = tid & 63, wave = tid >> 6;
    const int quad = lane >> 4, l16 = lane & 15;
    const int wcol = wave * 32;

    f32x4 acc[4][2];
#pragma unroll
    for (int mt = 0; mt < 4; mt++)
#pragma unroll
        for (int nt = 0; nt < 2; nt++) acc[mt][nt] = (f32x4){0.f, 0.f, 0.f, 0.f};

#pragma unroll
    for (int kc = 0; kc < 4; kc++) {
        short8 a[4], b[2];
#pragma unroll
        for (int mt = 0; mt < 4; mt++)
            a[mt] = *(const short8*)(As + (size_t)(mt * 16 + l16) * KP + kc * 32 + quad * 8);
#pragma unroll
        for (int nt = 0; nt < 2; nt++)
            b[nt] = *(const short8*)(Bs + (size_t)(wcol + nt * 16 + l16) * KP + kc * 32 + quad * 8);
#pragma unroll
        for (int mt = 0; mt < 4; mt++)
#pragma unroll
            for (int nt = 0; nt < 2; nt++)
                acc[mt][nt] = __builtin_amdgcn_mfma_f32_16x16x32_bf16(a[mt], b[nt], acc[mt][nt], 0, 0, 0);
    }

    __syncthreads();
#pragma unroll
    for (int mt = 0; mt < 4; mt++)
#pragma unroll
        for (int i = 0; i < 4; i++) {
            int rl = mt * 16 + quad * 4 + i;
#pragma unroll
            for (int nt = 0; nt < 2; nt++)
                As[rl * KP + wcol + nt * 16 + l16] = f2bf(acc[mt][nt][i]);
        }
    __syncthreads();
#pragma unroll
    for (int it = 0; it < 4; it++) {
        int idx = tid + it * 256;
        int r = idx >> 4, c8 = idx & 15;
        if (row0 + r <= M)                             // <= M: row M = zero pad row
            *(uint4*)(C + (size_t)(row0 + r) * NCOLS + col0 + c8 * 8) =
                *(const uint4*)(As + r * KP + c8 * 8);
    }
}

// ---------------- 128-col aggregation (node-range chunk: node = n0 + blockIdx*4 + wave) ----------------
template <bool RELU>
__global__ __launch_bounds__(256) void agg128f_k(const u16* __restrict__ out2,
                                                 const int* __restrict__ colsF,
                                                 const float* __restrict__ invd,
                                                 const float* __restrict__ bias,
                                                 const uint2* __restrict__ pool,
                                                 const int* __restrict__ gcnt,
                                                 u16* __restrict__ outp, int n0, int Mn) {
    int wave = threadIdx.x >> 6, lane = threadIdx.x & 63;
    int node = n0 + blockIdx.x * 4 + wave;
    if (node >= Mn) return;
    int sub = lane >> 4, l16 = lane & 15;
    const u16* tb = out2 + 128 + 8 * l16;
    const int* cp = colsF + node * 32 + sub;
    int s0 = cp[0],  s1 = cp[4],  s2 = cp[8],  s3 = cp[12];
    int s4 = cp[16], s5 = cp[20], s6 = cp[24], s7 = cp[28];
    const int deg = __builtin_amdgcn_readfirstlane(s0 >> 17);   // wave-uniform degree -> SGPR
    s0 &= IDXMASK; s1 &= IDXMASK; s2 &= IDXMASK; s3 &= IDXMASK;
    s4 &= IDXMASK; s5 &= IDXMASK; s6 &= IDXMASK; s7 &= IDXMASK;
    float id = invd[node];
    uint4 sv = *(const uint4*)(out2 + (size_t)node * 256 + 8 * l16);
    float4 b0 = *(const float4*)(bias + 8 * l16);
    float4 b1 = *(const float4*)(bias + 8 * l16 + 4);
    uint4 v0 = *(const uint4*)(tb + (size_t)s0 * 256);
    uint4 v1 = *(const uint4*)(tb + (size_t)s1 * 256);
    uint4 v2 = *(const uint4*)(tb + (size_t)s2 * 256);
    uint4 v3 = *(const uint4*)(tb + (size_t)s3 * 256);
    uint4 v4 = *(const uint4*)(tb + (size_t)s4 * 256);
    uint4 v5 = *(const uint4*)(tb + (size_t)s5 * 256);
    uint4 v6 = *(const uint4*)(tb + (size_t)s6 * 256);
    uint4 v7 = *(const uint4*)(tb + (size_t)s7 * 256);
    float2 a[4];
#pragma unroll
    for (int i = 0; i < 4; i++) a[i] = make_float2(0.f, 0.f);
    acc_u4p(a, v0);
    if (deg > 4)  acc_u4p(a, v1);
    if (deg > 8)  acc_u4p(a, v2);
    if (deg > 12) acc_u4p(a, v3);
    if (deg > 16) {
        acc_u4p(a, v4);
        if (deg > 20) acc_u4p(a, v5);
        if (deg > 24) acc_u4p(a, v6);
        if (deg > 28) acc_u4p(a, v7);
    }
    if (deg > 32) {                                    // in-kernel overflow (rare, scalar branch)
        int cnt = min(*gcnt, POOLCAP);
        for (int j = 0; j < cnt; j++) {
            uint2 pe = pool[j];
            if ((int)pe.x == node && sub == (j & 3))
                acc_u4p(a, *(const uint4*)(tb + (size_t)pe.y * 256));
        }
    }
    float af[8] = {a[0].x, a[0].y, a[1].x, a[1].y, a[2].x, a[2].y, a[3].x, a[3].y};
#pragma unroll
    for (int j = 0; j < 8; j++) {
        af[j] += __shfl_xor(af[j], 16); af[j] += __shfl_xor(af[j], 32);
    }
    if (sub == 0) {
        float o0 = bf2f(sv.x & 0xffffu) + af[0] * id + b0.x;
        float o1 = bf2f(sv.x >> 16)     + af[1] * id + b0.y;
        float o2 = bf2f(sv.y & 0xffffu) + af[2] * id + b0.z;
        float o3 = bf2f(sv.y >> 16)     + af[3] * id + b0.w;
        float o4 = bf2f(sv.z & 0xffffu) + af[4] * id + b1.x;
        float o5 = bf2f(sv.z >> 16)     + af[5] * id + b1.y;
        float o6 = bf2f(sv.w & 0xffffu) + af[6] * id + b1.z;
        float o7 = bf2f(sv.w >> 16)     + af[7] * id + b1.w;
        if (RELU) {
            o0 = fmaxf(o0, 0.f); o1 = fmaxf(o1, 0.f); o2 = fmaxf(o2, 0.f); o3 = fmaxf(o3, 0.f);
            o4 = fmaxf(o4, 0.f); o5 = fmaxf(o5, 0.f); o6 = fmaxf(o6, 0.f); o7 = fmaxf(o7, 0.f);
        }
        uint4 w;
        w.x = (u32)f2bf(o0) | ((u32)f2bf(o1) << 16);
        w.y = (u32)f2bf(o2) | ((u32)f2bf(o3) << 16);
        w.z = (u32)f2bf(o4) | ((u32)f2bf(o5) << 16);
        w.w = (u32)f2bf(o6) | ((u32)f2bf(o7) << 16);
        *(uint4*)(outp + (size_t)node * 128 + 8 * l16) = w;
    }
}

// ---------------- layer-2 aggregation (node-range chunk) ----------------
__global__ __launch_bounds__(256) void agg_out8f_k(const u16* __restrict__ out2,
                                                   const int* __restrict__ colsF,
                                                   const float* __restrict__ invd,
                                                   const float* __restrict__ bias,
                                                   const uint2* __restrict__ pool,
                                                   const int* __restrict__ gcnt,
                                                   float* __restrict__ outp, int n0, int Mn) {
    int wave = threadIdx.x >> 6, lane = threadIdx.x & 63;
    int node = n0 + blockIdx.x * 4 + wave;
    if (node >= Mn) return;
    int e8 = lane >> 3, l8 = lane & 7;
    const u16* tb = out2 + 64 + 8 * l8;
    const int* cp = colsF + node * 32 + e8;
    int s0 = cp[0], s1 = cp[8], s2 = cp[16], s3 = cp[24];
    const int deg = __builtin_amdgcn_readfirstlane(s0 >> 17);
    s0 &= IDXMASK; s1 &= IDXMASK; s2 &= IDXMASK; s3 &= IDXMASK;
    float id = invd[node];
    uint4 sv = *(const uint4*)(out2 + (size_t)node * 128 + 8 * l8);
    uint4 v0 = *(const uint4*)(tb + (size_t)s0 * 128);
    uint4 v1 = *(const uint4*)(tb + (size_t)s1 * 128);
    uint4 v2 = *(const uint4*)(tb + (size_t)s2 * 128);
    uint4 v3 = *(const uint4*)(tb + (size_t)s3 * 128);
    float2 a[4];
#pragma unroll
    for (int i = 0; i < 4; i++) a[i] = make_float2(0.f, 0.f);
    acc_u4p(a, v0);
    if (deg > 8)  acc_u4p(a, v1);
    if (deg > 16) acc_u4p(a, v2);
    if (deg > 24) acc_u4p(a, v3);
    if (deg > 32) {                                    // in-kernel overflow (rare)
        int cnt = min(*gcnt, POOLCAP);
        for (int j = 0; j < cnt; j++) {
            uint2 pe = pool[j];
            if ((int)pe.x == node && e8 == (j & 7))
                acc_u4p(a, *(const uint4*)(tb + (size_t)pe.y * 128));
        }
    }
    float af[8] = {a[0].x, a[0].y, a[1].x, a[1].y, a[2].x, a[2].y, a[3].x, a[3].y};
#pragma unroll
    for (int j = 0; j < 8; j++) {
        af[j] += __shfl_xor(af[j], 8); af[j] += __shfl_xor(af[j], 16); af[j] += __shfl_xor(af[j], 32);
    }
    if (e8 == 0) {
        u32 sw[4] = {sv.x, sv.y, sv.z, sv.w};
        float* orow = outp + (size_t)node * 47;
#pragma unroll
        for (int j = 0; j < 8; j++) {
            int c = 8 * l8 + j;
            if (c < 47) {
                float s = bf2f((j & 1) ? (sw[j >> 1] >> 16) : (sw[j >> 1] & 0xffffu));
                orow[c] = s + af[j] * id + bias[c];
            }
        }
    }
}

// ---------------- launch ----------------

extern "C" void kernel_launch(void* const* d_in, const int* in_sizes, int n_in,
                              void* d_out, int out_size, void* d_ws, size_t ws_size,
                              hipStream_t stream) {
    const float* x   = (const float*)d_in[0];
    const int*   src = (const int*)d_in[1];
    const int*   dst = (const int*)d_in[2];
    const float* ws0 = (const float*)d_in[3];
    const float* wn0 = (const float*)d_in[4];
    const float* b0  = (const float*)d_in[5];
    const float* ws1 = (const float*)d_in[6];
    const float* wn1 = (const float*)d_in[7];
    const float* b1  = (const float*)d_in[8];
    const float* ws2 = (const float*)d_in[9];
    const float* wn2 = (const float*)d_in[10];
    const float* b2  = (const float*)d_in[11];

    const int Nn = in_sizes[0] / 128;   // 100000
    const int E  = in_sizes[1];         // 1600000
    const int nBuckets = (Nn + 511) / 512;
    const int NnPad = nBuckets * 512;
    const int nRowTiles = (Nn + 63) / 64;
    const int NS = (E + TILE - 1) / TILE;              // scatter blocks

    char* p = (char*)d_ws;
    auto alloc = [&](size_t bytes) -> void* {
        void* r = (void*)p;
        p += (bytes + 255) & ~(size_t)255;
        return r;
    };
    u16*   bufA   = (u16*)alloc((size_t)Nn * 128 * 2);            // h1 / h2; pairs overlay (dead until agg0)
    u16*   out2   = (u16*)alloc(((size_t)Nn * 256 + 256) * 2);    // [s|t] per layer + zero pad row
    u16*   wt0    = (u16*)alloc(256 * 128 * 2);
    u16*   wt1    = (u16*)alloc(256 * 128 * 2);
    u16*   wt2    = (u16*)alloc(128 * 128 * 2);
    float* invd   = (float*)alloc((size_t)Nn * 4);
    int*   colsF  = (int*)alloc((size_t)NnPad * 32 * 4);          // fixed-stride edge table (deg<<17|src)
    uint2* pool   = (uint2*)alloc((size_t)POOLCAP * 8);           // deg>32 overflow
    int*   ctrl   = (int*)alloc(257 * 4);                         // cursor[256] + gcnt (one memset)
    int*   cursor = ctrl;
    int*   gcnt   = ctrl + 256;
    uint2* pairs  = (uint2*)bufA;                                 // 256*BUCKCAP*8 = 25.17 MB <= bufA 25.6 MB

    hipMemsetAsync(ctrl, 0, 257 * 4, stream);

    // fused: lean bucket scatter (NS blocks) + weight prep (160 blocks)
    scatter_prep<<<NS + 160, 512, 0, stream>>>(src, dst, cursor, pairs, E, NS,
                                               ws0, wn0, wt0, ws1, wn1, wt1, ws2, wn2, wt2);
    build_csr3<<<nBuckets, 512, 0, stream>>>(pairs, cursor, invd, colsF, pool, gcnt, Nn);

    dim3 ggrid(nRowTiles, 2);
    dim3 ggrid1(nRowTiles, 1);
    // DIAGNOSTIC ROUND: each agg split into 4 node-range quarters so the top-5
    // duration cutoff drops to ~16 us and non-agg kernels surface with counters.
    const int quarterN = ((Nn + 15) / 16) * 4;           // 25000, multiple of 4
    auto agg128_q = [&](const float* bias) {
        for (int q = 0; q < 4; q++) {
            int start = q * quarterN;
            if (start >= Nn) break;
            int count = min(quarterN, Nn - start);
            agg128f_k<true><<<(count + 3) / 4, 256, 0, stream>>>(out2, colsF, invd, bias,
                                                                 pool, gcnt, bufA, start, Nn);
        }
    };
    // layer 0 (gemm writes the zero pad row at node Nn itself)
    gemm_bf16<256, true><<<ggrid, 256, 0, stream>>>(x, wt0, out2, Nn);
    agg128_q(b0);
    // layer 1
    gemm_bf16<256, false><<<ggrid, 256, 0, stream>>>(bufA, wt1, out2, Nn);
    agg128_q(b1);
    // layer 2
    gemm_bf16<128, false><<<ggrid1, 256, 0, stream>>>(bufA, wt2, out2, Nn);
    for (int q = 0; q < 4; q++) {
        int start = q * quarterN;
        if (start >= Nn) break;
        int count = min(quarterN, Nn - start);
        agg_out8f_k<<<(count + 3) / 4, 256, 0, stream>>>(out2, colsF, invd, b2,
                                                         pool, gcnt, (float*)d_out, start, Nn);
    }
}

// Round 12
// 366.876 us; speedup vs baseline: 1.1319x; 1.1319x over previous
//
#include <hip/hip_runtime.h>

typedef unsigned int u32;
typedef unsigned short u16;
typedef __attribute__((ext_vector_type(8))) short short8;   // 8 x bf16 (guide-verified frag type)
typedef __attribute__((ext_vector_type(4))) float f32x4;

#define POOLCAP 65536
#define IDXMASK 0x1ffff   // src index lives in bits 0..16; deg in bits 17..31
#define BUCKCAP 12288     // fixed pairs segment per bucket (mean 8192, sigma~90 -> +45 sigma)

__device__ __forceinline__ u16 f2bf(float f) {
    u32 u = __float_as_uint(f);
    u32 r = (u + 0x7fffu + ((u >> 16) & 1u)) >> 16;   // RNE
    return (u16)r;
}
__device__ __forceinline__ float bf2f(u32 lo16) { return __uint_as_float(lo16 << 16); }

// packed accumulate: a[i] += {lo(w), hi(w)}
__device__ __forceinline__ void acc_u4p(float2* a, uint4 v) {
    u32 w[4] = {v.x, v.y, v.z, v.w};
#pragma unroll
    for (int i = 0; i < 4; i++) {
        a[i].x += __uint_as_float(w[i] << 16);
        a[i].y += __uint_as_float(w[i] & 0xffff0000u);
    }
}

// ---------------- prep: transposed weights (blocks 0..159) + ctrl zero (block 160) ----------------
__global__ __launch_bounds__(512) void prep_ctrl(const float* __restrict__ ws0, const float* __restrict__ wn0, u16* __restrict__ wt0,
                                                 const float* __restrict__ ws1, const float* __restrict__ wn1, u16* __restrict__ wt1,
                                                 const float* __restrict__ ws2, const float* __restrict__ wn2, u16* __restrict__ wt2,
                                                 int* __restrict__ ctrl) {
    int local = blockIdx.x;
    if (local >= 160) {                                // ---- ctrl zero (cursor[256] + gcnt) ----
        if (threadIdx.x < 257) ctrl[threadIdx.x] = 0;
        return;
    }
    const float *ws, *wn;
    u16* wt;
    int dout, HW;
    if (local < 64)       { ws = ws0; wn = wn0; wt = wt0; dout = 128; HW = 128; }
    else if (local < 128) { ws = ws1; wn = wn1; wt = wt1; dout = 128; HW = 128; local -= 64; }
    else                  { ws = ws2; wn = wn2; wt = wt2; dout = 47;  HW = 64;  local -= 128; }
    int idx = local * 512 + threadIdx.x;               // idx = n*128 + k
    int n = idx >> 7, k = idx & 127;
    float v = 0.f;
    if (n < HW) { if (n < dout) v = ws[k * dout + n]; }
    else { int nn = n - HW; if (nn < dout) v = wn[k * dout + nn]; }
    wt[idx] = f2bf(v);
}

// ---------------- fused: lean scatter (blocks [0,NS)) + gemm layer 0 (rest) ----------------
// Independent halves run concurrently in one dispatch: scatter reads src/dst, writes
// pairs(=bufA overlay)+cursor; gemm0 reads x/wt0 (prepped in prep_ctrl), writes out2.
// Disjoint memory. 256 threads/block; LDS union (scatter uses 2KB of the gemm's 51KB).
#define TILE 4096
#define KDIM 128
#define KP 136
#define GEMM_LDS (64 * KP * 2 + 128 * KP * 2)          // 52224 B

__global__ __launch_bounds__(256) void scatter_gemm0(const int* __restrict__ src,
                                                     const int* __restrict__ dst,
                                                     int* __restrict__ cursor,
                                                     uint2* __restrict__ pairs, int E, int NS,
                                                     const float* __restrict__ x,
                                                     const u16* __restrict__ Bt,
                                                     u16* __restrict__ C,
                                                     int Nn, int nRowTiles) {
    __shared__ __align__(16) char lds[GEMM_LDS];
    const int tid = threadIdx.x;

    if (blockIdx.x < NS) {                             // ================ lean scatter ================
        int* s_cnt  = (int*)lds;                       // [256]
        int* s_gpos = (int*)(lds + 1024);              // [256]
        const int base = blockIdx.x * TILE;
        const int tn = min(TILE, E - base);
        s_cnt[tid] = 0;
        __syncthreads();
        int d[16], s[16], r[16];
#pragma unroll
        for (int j = 0; j < 16; j++) {
            int k = tid + j * 256;
            if (k < tn) {
                d[j] = dst[base + k];
                s[j] = src[base + k];
                r[j] = atomicAdd(&s_cnt[d[j] >> 9], 1);  // rank = final within-block slot
            } else d[j] = -1;
        }
        __syncthreads();
        if (s_cnt[tid] > 0) s_gpos[tid] = atomicAdd(&cursor[tid], s_cnt[tid]);
        __syncthreads();
#pragma unroll
        for (int j = 0; j < 16; j++) {
            if (d[j] >= 0) {
                int b = d[j] >> 9;
                int pos = s_gpos[b] + r[j];
                if (pos < BUCKCAP)                     // overflow guard (~0 probability)
                    pairs[(size_t)b * BUCKCAP + pos] = make_uint2((u32)d[j], (u32)s[j]);
            }
        }
        return;
    }
    // ================ gemm layer 0 (AF32 A, NCOLS=256) ================
    u16* As = (u16*)lds;                               // [64*KP]
    u16* Bs = (u16*)(lds + 64 * KP * 2);               // [128*KP]
    const int g = blockIdx.x - NS;
    const int row0 = (g % nRowTiles) * 64;
    const int col0 = (g / nRowTiles) * 128;
    const int M = Nn;

#pragma unroll
    for (int i = 0; i < 4; i++) {
        int idx = tid + i * 256;
        int r = idx >> 4, c = idx & 15;
        uint4 v = make_uint4(0, 0, 0, 0);
        if (row0 + r < M) {
            const float4* rowp = (const float4*)(x + (size_t)(row0 + r) * KDIM);
            float4 f0 = rowp[2 * c];
            float4 f1 = rowp[2 * c + 1];
            v.x = (u32)f2bf(f0.x) | ((u32)f2bf(f0.y) << 16);
            v.y = (u32)f2bf(f0.z) | ((u32)f2bf(f0.w) << 16);
            v.z = (u32)f2bf(f1.x) | ((u32)f2bf(f1.y) << 16);
            v.w = (u32)f2bf(f1.z) | ((u32)f2bf(f1.w) << 16);
        }
        ((uint4*)(As + r * KP))[c] = v;
    }
#pragma unroll
    for (int i = 0; i < 8; i++) {
        int idx = tid + i * 256;
        int r = idx >> 4, c = idx & 15;
        uint4 v = ((const uint4*)(Bt + (size_t)(col0 + r) * KDIM))[c];
        ((uint4*)(Bs + r * KP))[c] = v;
    }
    __syncthreads();

    const int lane = tid & 63, wave = tid >> 6;
    const int quad = lane >> 4, l16 = lane & 15;
    const int wcol = wave * 32;

    f32x4 acc[4][2];
#pragma unroll
    for (int mt = 0; mt < 4; mt++)
#pragma unroll
        for (int nt = 0; nt < 2; nt++) acc[mt][nt] = (f32x4){0.f, 0.f, 0.f, 0.f};

#pragma unroll
    for (int kc = 0; kc < 4; kc++) {
        short8 a[4], bfr[2];
#pragma unroll
        for (int mt = 0; mt < 4; mt++)
            a[mt] = *(const short8*)(As + (size_t)(mt * 16 + l16) * KP + kc * 32 + quad * 8);
#pragma unroll
        for (int nt = 0; nt < 2; nt++)
            bfr[nt] = *(const short8*)(Bs + (size_t)(wcol + nt * 16 + l16) * KP + kc * 32 + quad * 8);
#pragma unroll
        for (int mt = 0; mt < 4; mt++)
#pragma unroll
            for (int nt = 0; nt < 2; nt++)
                acc[mt][nt] = __builtin_amdgcn_mfma_f32_16x16x32_bf16(a[mt], bfr[nt], acc[mt][nt], 0, 0, 0);
    }

    __syncthreads();
#pragma unroll
    for (int mt = 0; mt < 4; mt++)
#pragma unroll
        for (int i = 0; i < 4; i++) {
            int rl = mt * 16 + quad * 4 + i;
#pragma unroll
            for (int nt = 0; nt < 2; nt++)
                As[rl * KP + wcol + nt * 16 + l16] = f2bf(acc[mt][nt][i]);
        }
    __syncthreads();
#pragma unroll
    for (int it = 0; it < 4; it++) {
        int idx = tid + it * 256;
        int r = idx >> 4, c8 = idx & 15;
        if (row0 + r <= M)                             // <= M: row M = zero pad row
            *(uint4*)(C + (size_t)(row0 + r) * 256 + col0 + c8 * 8) =
                *(const uint4*)(As + r * KP + c8 * 8);
    }
}

// ---------------- build: FIXED-STRIDE placement, single pass over pairs ----------------
__global__ __launch_bounds__(512) void build_csr3(const uint2* __restrict__ pairs,
                                                  const int* __restrict__ cursor,
                                                  float* __restrict__ invd,
                                                  int* __restrict__ colsF,
                                                  uint2* __restrict__ pool,
                                                  int* __restrict__ gcnt,
                                                  int Nn) {
    __shared__ int s_fix[512 * 32];                    // 64 KB fixed table
    __shared__ int s_cnt[512];
    const int tid = threadIdx.x;
    const int d0 = blockIdx.x * 512;
    const int nd = min(512, Nn - d0);
    const size_t base = (size_t)blockIdx.x * BUCKCAP;
    const int n = min(cursor[blockIdx.x], BUCKCAP);
    s_cnt[tid] = 0;
    __syncthreads();
    for (int k = tid; k < n; k += 512) {               // single read of pairs, direct place
        uint2 pr = pairs[base + k];
        int dl = (int)pr.x - d0;
        int p = atomicAdd(&s_cnt[dl], 1);
        if (p < 32) s_fix[dl * 32 + p] = (int)pr.y;
        else {
            int q = atomicAdd(gcnt, 1);
            if (q < POOLCAP) pool[q] = make_uint2(pr.x, pr.y);
        }
    }
    __syncthreads();
    if (tid < nd) invd[d0 + tid] = 1.0f / (float)max(s_cnt[tid], 1);
    // coalesced writeback; sentinels + deg tag synthesized on the fly
    int4* dst4 = (int4*)(colsF + (size_t)d0 * 32);
    for (int k = tid; k < 512 * 32 / 4; k += 512) {
        int node = k >> 3;                             // 8 int4 per node
        int cnt = s_cnt[node];
        int dg = min(cnt, 0x7fff) << 17;
        int sb = (k & 7) * 4;
        int4 v;
        v.x = ((sb + 0 < cnt) ? s_fix[k * 4 + 0] : Nn) | dg;
        v.y = ((sb + 1 < cnt) ? s_fix[k * 4 + 1] : Nn) | dg;
        v.z = ((sb + 2 < cnt) ? s_fix[k * 4 + 2] : Nn) | dg;
        v.w = ((sb + 3 < cnt) ? s_fix[k * 4 + 3] : Nn) | dg;
        dst4[k] = v;
    }
}

// ---------------- standalone GEMM (layers 1-2): C[M][NCOLS] = A[M][128] @ Bt^T ----------------
template <int NCOLS, bool AF32>
__global__ __launch_bounds__(256) void gemm_bf16(const void* __restrict__ Ap,
                                                 const u16* __restrict__ Bt,
                                                 u16* __restrict__ C, int M) {
    __shared__ u16 As[64 * KP];
    __shared__ u16 Bs[128 * KP];
    const int row0 = blockIdx.x * 64;
    const int col0 = blockIdx.y * 128;
    const int tid = threadIdx.x;

#pragma unroll
    for (int i = 0; i < 4; i++) {
        int idx = tid + i * 256;
        int r = idx >> 4, c = idx & 15;
        uint4 v = make_uint4(0, 0, 0, 0);
        if (row0 + r < M) {
            if (AF32) {
                const float* Af = (const float*)Ap;
                const float4* rowp = (const float4*)(Af + (size_t)(row0 + r) * KDIM);
                float4 f0 = rowp[2 * c];
                float4 f1 = rowp[2 * c + 1];
                v.x = (u32)f2bf(f0.x) | ((u32)f2bf(f0.y) << 16);
                v.y = (u32)f2bf(f0.z) | ((u32)f2bf(f0.w) << 16);
                v.z = (u32)f2bf(f1.x) | ((u32)f2bf(f1.y) << 16);
                v.w = (u32)f2bf(f1.z) | ((u32)f2bf(f1.w) << 16);
            } else {
                const u16* Ab = (const u16*)Ap;
                v = ((const uint4*)(Ab + (size_t)(row0 + r) * KDIM))[c];
            }
        }
        ((uint4*)(As + r * KP))[c] = v;
    }
#pragma unroll
    for (int i = 0; i < 8; i++) {
        int idx = tid + i * 256;
        int r = idx >> 4, c = idx & 15;
        uint4 v = ((const uint4*)(Bt + (size_t)(col0 + r) * KDIM))[c];
        ((uint4*)(Bs + r * KP))[c] = v;
    }
    __syncthreads();

    const int lane = tid & 63, wave = tid >> 6;
    const int quad = lane >> 4, l16 = lane & 15;
    const int wcol = wave * 32;

    f32x4 acc[4][2];
#pragma unroll
    for (int mt = 0; mt < 4; mt++)
#pragma unroll
        for (int nt = 0; nt < 2; nt++) acc[mt][nt] = (f32x4){0.f, 0.f, 0.f, 0.f};

#pragma unroll
    for (int kc = 0; kc < 4; kc++) {
        short8 a[4], b[2];
#pragma unroll
        for (int mt = 0; mt < 4; mt++)
            a[mt] = *(const short8*)(As + (size_t)(mt * 16 + l16) * KP + kc * 32 + quad * 8);
#pragma unroll
        for (int nt = 0; nt < 2; nt++)
            b[nt] = *(const short8*)(Bs + (size_t)(wcol + nt * 16 + l16) * KP + kc * 32 + quad * 8);
#pragma unroll
        for (int mt = 0; mt < 4; mt++)
#pragma unroll
            for (int nt = 0; nt < 2; nt++)
                acc[mt][nt] = __builtin_amdgcn_mfma_f32_16x16x32_bf16(a[mt], b[nt], acc[mt][nt], 0, 0, 0);
    }

    __syncthreads();
#pragma unroll
    for (int mt = 0; mt < 4; mt++)
#pragma unroll
        for (int i = 0; i < 4; i++) {
            int rl = mt * 16 + quad * 4 + i;
#pragma unroll
            for (int nt = 0; nt < 2; nt++)
                As[rl * KP + wcol + nt * 16 + l16] = f2bf(acc[mt][nt][i]);
        }
    __syncthreads();
#pragma unroll
    for (int it = 0; it < 4; it++) {
        int idx = tid + it * 256;
        int r = idx >> 4, c8 = idx & 15;
        if (row0 + r <= M)                             // <= M: row M = zero pad row
            *(uint4*)(C + (size_t)(row0 + r) * NCOLS + col0 + c8 * 8) =
                *(const uint4*)(As + r * KP + c8 * 8);
    }
}

// ---------------- 128-col aggregation, fixed-stride + scalar deg-gating + in-kernel overflow ----------------
template <bool RELU>
__global__ __launch_bounds__(256) void agg128f_k(const u16* __restrict__ out2,
                                                 const int* __restrict__ colsF,
                                                 const float* __restrict__ invd,
                                                 const float* __restrict__ bias,
                                                 const uint2* __restrict__ pool,
                                                 const int* __restrict__ gcnt,
                                                 u16* __restrict__ outp, int Mn) {
    int wave = threadIdx.x >> 6, lane = threadIdx.x & 63;
    int node = blockIdx.x * 4 + wave;
    if (node >= Mn) return;
    int sub = lane >> 4, l16 = lane & 15;
    const u16* tb = out2 + 128 + 8 * l16;
    const int* cp = colsF + node * 32 + sub;
    int s0 = cp[0],  s1 = cp[4],  s2 = cp[8],  s3 = cp[12];
    int s4 = cp[16], s5 = cp[20], s6 = cp[24], s7 = cp[28];
    const int deg = __builtin_amdgcn_readfirstlane(s0 >> 17);   // wave-uniform degree -> SGPR
    s0 &= IDXMASK; s1 &= IDXMASK; s2 &= IDXMASK; s3 &= IDXMASK;
    s4 &= IDXMASK; s5 &= IDXMASK; s6 &= IDXMASK; s7 &= IDXMASK;
    float id = invd[node];
    uint4 sv = *(const uint4*)(out2 + (size_t)node * 256 + 8 * l16);
    float4 b0 = *(const float4*)(bias + 8 * l16);
    float4 b1 = *(const float4*)(bias + 8 * l16 + 4);
    uint4 v0 = *(const uint4*)(tb + (size_t)s0 * 256);
    uint4 v1 = *(const uint4*)(tb + (size_t)s1 * 256);
    uint4 v2 = *(const uint4*)(tb + (size_t)s2 * 256);
    uint4 v3 = *(const uint4*)(tb + (size_t)s3 * 256);
    uint4 v4 = *(const uint4*)(tb + (size_t)s4 * 256);
    uint4 v5 = *(const uint4*)(tb + (size_t)s5 * 256);
    uint4 v6 = *(const uint4*)(tb + (size_t)s6 * 256);
    uint4 v7 = *(const uint4*)(tb + (size_t)s7 * 256);
    float2 a[4];
#pragma unroll
    for (int i = 0; i < 4; i++) a[i] = make_float2(0.f, 0.f);
    acc_u4p(a, v0);
    if (deg > 4)  acc_u4p(a, v1);
    if (deg > 8)  acc_u4p(a, v2);
    if (deg > 12) acc_u4p(a, v3);
    if (deg > 16) {
        acc_u4p(a, v4);
        if (deg > 20) acc_u4p(a, v5);
        if (deg > 24) acc_u4p(a, v6);
        if (deg > 28) acc_u4p(a, v7);
    }
    if (deg > 32) {                                    // in-kernel overflow (rare, scalar branch)
        int cnt = min(*gcnt, POOLCAP);
        for (int j = 0; j < cnt; j++) {
            uint2 pe = pool[j];
            if ((int)pe.x == node && sub == (j & 3))
                acc_u4p(a, *(const uint4*)(tb + (size_t)pe.y * 256));
        }
    }
    float af[8] = {a[0].x, a[0].y, a[1].x, a[1].y, a[2].x, a[2].y, a[3].x, a[3].y};
#pragma unroll
    for (int j = 0; j < 8; j++) {
        af[j] += __shfl_xor(af[j], 16); af[j] += __shfl_xor(af[j], 32);
    }
    if (sub == 0) {
        float o0 = bf2f(sv.x & 0xffffu) + af[0] * id + b0.x;
        float o1 = bf2f(sv.x >> 16)     + af[1] * id + b0.y;
        float o2 = bf2f(sv.y & 0xffffu) + af[2] * id + b0.z;
        float o3 = bf2f(sv.y >> 16)     + af[3] * id + b0.w;
        float o4 = bf2f(sv.z & 0xffffu) + af[4] * id + b1.x;
        float o5 = bf2f(sv.z >> 16)     + af[5] * id + b1.y;
        float o6 = bf2f(sv.w & 0xffffu) + af[6] * id + b1.z;
        float o7 = bf2f(sv.w >> 16)     + af[7] * id + b1.w;
        if (RELU) {
            o0 = fmaxf(o0, 0.f); o1 = fmaxf(o1, 0.f); o2 = fmaxf(o2, 0.f); o3 = fmaxf(o3, 0.f);
            o4 = fmaxf(o4, 0.f); o5 = fmaxf(o5, 0.f); o6 = fmaxf(o6, 0.f); o7 = fmaxf(o7, 0.f);
        }
        uint4 w;
        w.x = (u32)f2bf(o0) | ((u32)f2bf(o1) << 16);
        w.y = (u32)f2bf(o2) | ((u32)f2bf(o3) << 16);
        w.z = (u32)f2bf(o4) | ((u32)f2bf(o5) << 16);
        w.w = (u32)f2bf(o6) | ((u32)f2bf(o7) << 16);
        *(uint4*)(outp + (size_t)node * 128 + 8 * l16) = w;
    }
}

// ---------------- layer-2 aggregation, fixed-stride + scalar deg-gating + in-kernel overflow ----------------
__global__ __launch_bounds__(256) void agg_out8f_k(const u16* __restrict__ out2,
                                                   const int* __restrict__ colsF,
                                                   const float* __restrict__ invd,
                                                   const float* __restrict__ bias,
                                                   const uint2* __restrict__ pool,
                                                   const int* __restrict__ gcnt,
                                                   float* __restrict__ outp, int Mn) {
    int wave = threadIdx.x >> 6, lane = threadIdx.x & 63;
    int node = blockIdx.x * 4 + wave;
    if (node >= Mn) return;
    int e8 = lane >> 3, l8 = lane & 7;
    const u16* tb = out2 + 64 + 8 * l8;
    const int* cp = colsF + node * 32 + e8;
    int s0 = cp[0], s1 = cp[8], s2 = cp[16], s3 = cp[24];
    const int deg = __builtin_amdgcn_readfirstlane(s0 >> 17);
    s0 &= IDXMASK; s1 &= IDXMASK; s2 &= IDXMASK; s3 &= IDXMASK;
    float id = invd[node];
    uint4 sv = *(const uint4*)(out2 + (size_t)node * 128 + 8 * l8);
    uint4 v0 = *(const uint4*)(tb + (size_t)s0 * 128);
    uint4 v1 = *(const uint4*)(tb + (size_t)s1 * 128);
    uint4 v2 = *(const uint4*)(tb + (size_t)s2 * 128);
    uint4 v3 = *(const uint4*)(tb + (size_t)s3 * 128);
    float2 a[4];
#pragma unroll
    for (int i = 0; i < 4; i++) a[i] = make_float2(0.f, 0.f);
    acc_u4p(a, v0);
    if (deg > 8)  acc_u4p(a, v1);
    if (deg > 16) acc_u4p(a, v2);
    if (deg > 24) acc_u4p(a, v3);
    if (deg > 32) {                                    // in-kernel overflow (rare)
        int cnt = min(*gcnt, POOLCAP);
        for (int j = 0; j < cnt; j++) {
            uint2 pe = pool[j];
            if ((int)pe.x == node && e8 == (j & 7))
                acc_u4p(a, *(const uint4*)(tb + (size_t)pe.y * 128));
        }
    }
    float af[8] = {a[0].x, a[0].y, a[1].x, a[1].y, a[2].x, a[2].y, a[3].x, a[3].y};
#pragma unroll
    for (int j = 0; j < 8; j++) {
        af[j] += __shfl_xor(af[j], 8); af[j] += __shfl_xor(af[j], 16); af[j] += __shfl_xor(af[j], 32);
    }
    if (e8 == 0) {
        u32 sw[4] = {sv.x, sv.y, sv.z, sv.w};
        float* orow = outp + (size_t)node * 47;
#pragma unroll
        for (int j = 0; j < 8; j++) {
            int c = 8 * l8 + j;
            if (c < 47) {
                float s = bf2f((j & 1) ? (sw[j >> 1] >> 16) : (sw[j >> 1] & 0xffffu));
                orow[c] = s + af[j] * id + bias[c];
            }
        }
    }
}

// ---------------- launch ----------------

extern "C" void kernel_launch(void* const* d_in, const int* in_sizes, int n_in,
                              void* d_out, int out_size, void* d_ws, size_t ws_size,
                              hipStream_t stream) {
    const float* x   = (const float*)d_in[0];
    const int*   src = (const int*)d_in[1];
    const int*   dst = (const int*)d_in[2];
    const float* ws0 = (const float*)d_in[3];
    const float* wn0 = (const float*)d_in[4];
    const float* b0  = (const float*)d_in[5];
    const float* ws1 = (const float*)d_in[6];
    const float* wn1 = (const float*)d_in[7];
    const float* b1  = (const float*)d_in[8];
    const float* ws2 = (const float*)d_in[9];
    const float* wn2 = (const float*)d_in[10];
    const float* b2  = (const float*)d_in[11];

    const int Nn = in_sizes[0] / 128;   // 100000
    const int E  = in_sizes[1];         // 1600000
    const int nBuckets = (Nn + 511) / 512;
    const int NnPad = nBuckets * 512;
    const int nRowTiles = (Nn + 63) / 64;
    const int NS = (E + TILE - 1) / TILE;              // scatter blocks

    char* p = (char*)d_ws;
    auto alloc = [&](size_t bytes) -> void* {
        void* r = (void*)p;
        p += (bytes + 255) & ~(size_t)255;
        return r;
    };
    u16*   bufA   = (u16*)alloc((size_t)Nn * 128 * 2);            // h1 / h2; pairs overlay (dead until agg0)
    u16*   out2   = (u16*)alloc(((size_t)Nn * 256 + 256) * 2);    // [s|t] per layer + zero pad row
    u16*   wt0    = (u16*)alloc(256 * 128 * 2);
    u16*   wt1    = (u16*)alloc(256 * 128 * 2);
    u16*   wt2    = (u16*)alloc(128 * 128 * 2);
    float* invd   = (float*)alloc((size_t)Nn * 4);
    int*   colsF  = (int*)alloc((size_t)NnPad * 32 * 4);          // fixed-stride edge table (deg<<17|src)
    uint2* pool   = (uint2*)alloc((size_t)POOLCAP * 8);           // deg>32 overflow
    int*   ctrl   = (int*)alloc(257 * 4);                         // cursor[256] + gcnt
    int*   cursor = ctrl;
    int*   gcnt   = ctrl + 256;
    uint2* pairs  = (uint2*)bufA;                                 // 256*BUCKCAP*8 = 25.17 MB <= bufA 25.6 MB

    // 1: weight transpose + ctrl zero (no separate memset dispatch)
    prep_ctrl<<<161, 512, 0, stream>>>(ws0, wn0, wt0, ws1, wn1, wt1, ws2, wn2, wt2, ctrl);
    // 2: lean scatter CONCURRENT with gemm layer 0 (independent halves, one dispatch)
    scatter_gemm0<<<NS + nRowTiles * 2, 256, 0, stream>>>(src, dst, cursor, pairs, E, NS,
                                                          x, wt0, out2, Nn, nRowTiles);
    // 3: fixed-stride table build
    build_csr3<<<nBuckets, 512, 0, stream>>>(pairs, cursor, invd, colsF, pool, gcnt, Nn);

    dim3 ggrid(nRowTiles, 2);
    dim3 ggrid1(nRowTiles, 1);
    const int aggGrid = (Nn + 3) / 4;                    // 4 waves x 1 node
    // 4: layer 0 aggregation (writes bufA, clobbering consumed pairs)
    agg128f_k<true><<<aggGrid, 256, 0, stream>>>(out2, colsF, invd, b0, pool, gcnt, bufA, Nn);
    // 5-6: layer 1
    gemm_bf16<256, false><<<ggrid, 256, 0, stream>>>(bufA, wt1, out2, Nn);
    agg128f_k<true><<<aggGrid, 256, 0, stream>>>(out2, colsF, invd, b1, pool, gcnt, bufA, Nn);
    // 7-8: layer 2
    gemm_bf16<128, false><<<ggrid1, 256, 0, stream>>>(bufA, wt2, out2, Nn);
    agg_out8f_k<<<aggGrid, 256, 0, stream>>>(out2, colsF, invd, b2, pool, gcnt, (float*)d_out, Nn);
}

// Round 14
// 365.356 us; speedup vs baseline: 1.1366x; 1.0042x over previous
//
#include <hip/hip_runtime.h>

typedef unsigned int u32;
typedef unsigned short u16;
typedef __attribute__((ext_vector_type(8))) short short8;   // 8 x bf16 (guide-verified frag type)
typedef __attribute__((ext_vector_type(4))) float f32x4;

#define POOLCAP 65536
#define IDXMASK 0x1ffff   // src index lives in bits 0..16; deg in bits 17..31
#define BUCKCAP 12288     // fixed pairs segment per bucket (mean 8192, sigma~90 -> +45 sigma)

__device__ __forceinline__ u16 f2bf(float f) {
    u32 u = __float_as_uint(f);
    u32 r = (u + 0x7fffu + ((u >> 16) & 1u)) >> 16;   // RNE
    return (u16)r;
}
__device__ __forceinline__ float bf2f(u32 lo16) { return __uint_as_float(lo16 << 16); }

// packed accumulate: a[i] += {lo(w), hi(w)}
__device__ __forceinline__ void acc_u4p(float2* a, uint4 v) {
    u32 w[4] = {v.x, v.y, v.z, v.w};
#pragma unroll
    for (int i = 0; i < 4; i++) {
        a[i].x += __uint_as_float(w[i] << 16);
        a[i].y += __uint_as_float(w[i] & 0xffff0000u);
    }
}

// ---------------- prep: transposed weights (blocks 0..159) + ctrl zero (block 160) ----------------
__global__ __launch_bounds__(512) void prep_ctrl(const float* __restrict__ ws0, const float* __restrict__ wn0, u16* __restrict__ wt0,
                                                 const float* __restrict__ ws1, const float* __restrict__ wn1, u16* __restrict__ wt1,
                                                 const float* __restrict__ ws2, const float* __restrict__ wn2, u16* __restrict__ wt2,
                                                 int* __restrict__ ctrl) {
    int local = blockIdx.x;
    if (local >= 160) {                                // ---- ctrl zero (cursor[256] + gcnt) ----
        if (threadIdx.x < 257) ctrl[threadIdx.x] = 0;
        return;
    }
    const float *ws, *wn;
    u16* wt;
    int dout, HW;
    if (local < 64)       { ws = ws0; wn = wn0; wt = wt0; dout = 128; HW = 128; }
    else if (local < 128) { ws = ws1; wn = wn1; wt = wt1; dout = 128; HW = 128; local -= 64; }
    else                  { ws = ws2; wn = wn2; wt = wt2; dout = 47;  HW = 64;  local -= 128; }
    int idx = local * 512 + threadIdx.x;               // idx = n*128 + k
    int n = idx >> 7, k = idx & 127;
    float v = 0.f;
    if (n < HW) { if (n < dout) v = ws[k * dout + n]; }
    else { int nn = n - HW; if (nn < dout) v = wn[k * dout + nn]; }
    wt[idx] = f2bf(v);
}

// ---------------- fused: lean scatter (blocks [0,NS)) + gemm layer 0 (rest) ----------------
#define TILE 4096
#define KDIM 128
#define KP 136
#define GEMM_LDS (64 * KP * 2 + 128 * KP * 2)          // 52224 B

__global__ __launch_bounds__(256) void scatter_gemm0(const int* __restrict__ src,
                                                     const int* __restrict__ dst,
                                                     int* __restrict__ cursor,
                                                     uint2* __restrict__ pairs, int E, int NS,
                                                     const float* __restrict__ x,
                                                     const u16* __restrict__ Bt,
                                                     u16* __restrict__ C,
                                                     int Nn, int nRowTiles) {
    __shared__ __align__(16) char lds[GEMM_LDS];
    const int tid = threadIdx.x;

    if (blockIdx.x < NS) {                             // ================ lean scatter ================
        int* s_cnt  = (int*)lds;                       // [256]
        int* s_gpos = (int*)(lds + 1024);              // [256]
        const int base = blockIdx.x * TILE;
        const int tn = min(TILE, E - base);
        s_cnt[tid] = 0;
        __syncthreads();
        int d[16], s[16], r[16];
#pragma unroll
        for (int j = 0; j < 16; j++) {
            int k = tid + j * 256;
            if (k < tn) {
                d[j] = dst[base + k];
                s[j] = src[base + k];
                r[j] = atomicAdd(&s_cnt[d[j] >> 9], 1);  // rank = final within-block slot
            } else d[j] = -1;
        }
        __syncthreads();
        if (s_cnt[tid] > 0) s_gpos[tid] = atomicAdd(&cursor[tid], s_cnt[tid]);
        __syncthreads();
#pragma unroll
        for (int j = 0; j < 16; j++) {
            if (d[j] >= 0) {
                int b = d[j] >> 9;
                int pos = s_gpos[b] + r[j];
                if (pos < BUCKCAP)                     // overflow guard (~0 probability)
                    pairs[(size_t)b * BUCKCAP + pos] = make_uint2((u32)d[j], (u32)s[j]);
            }
        }
        return;
    }
    // ================ gemm layer 0 (AF32 A, NCOLS=256) ================
    u16* As = (u16*)lds;                               // [64*KP]
    u16* Bs = (u16*)(lds + 64 * KP * 2);               // [128*KP]
    const int g = blockIdx.x - NS;
    const int row0 = (g % nRowTiles) * 64;
    const int col0 = (g / nRowTiles) * 128;
    const int M = Nn;

#pragma unroll
    for (int i = 0; i < 4; i++) {
        int idx = tid + i * 256;
        int r = idx >> 4, c = idx & 15;
        uint4 v = make_uint4(0, 0, 0, 0);
        if (row0 + r < M) {
            const float4* rowp = (const float4*)(x + (size_t)(row0 + r) * KDIM);
            float4 f0 = rowp[2 * c];
            float4 f1 = rowp[2 * c + 1];
            v.x = (u32)f2bf(f0.x) | ((u32)f2bf(f0.y) << 16);
            v.y = (u32)f2bf(f0.z) | ((u32)f2bf(f0.w) << 16);
            v.z = (u32)f2bf(f1.x) | ((u32)f2bf(f1.y) << 16);
            v.w = (u32)f2bf(f1.z) | ((u32)f2bf(f1.w) << 16);
        }
        ((uint4*)(As + r * KP))[c] = v;
    }
#pragma unroll
    for (int i = 0; i < 8; i++) {
        int idx = tid + i * 256;
        int r = idx >> 4, c = idx & 15;
        uint4 v = ((const uint4*)(Bt + (size_t)(col0 + r) * KDIM))[c];
        ((uint4*)(Bs + r * KP))[c] = v;
    }
    __syncthreads();

    const int lane = tid & 63, wave = tid >> 6;
    const int quad = lane >> 4, l16 = lane & 15;
    const int wcol = wave * 32;

    f32x4 acc[4][2];
#pragma unroll
    for (int mt = 0; mt < 4; mt++)
#pragma unroll
        for (int nt = 0; nt < 2; nt++) acc[mt][nt] = (f32x4){0.f, 0.f, 0.f, 0.f};

#pragma unroll
    for (int kc = 0; kc < 4; kc++) {
        short8 a[4], bfr[2];
#pragma unroll
        for (int mt = 0; mt < 4; mt++)
            a[mt] = *(const short8*)(As + (size_t)(mt * 16 + l16) * KP + kc * 32 + quad * 8);
#pragma unroll
        for (int nt = 0; nt < 2; nt++)
            bfr[nt] = *(const short8*)(Bs + (size_t)(wcol + nt * 16 + l16) * KP + kc * 32 + quad * 8);
#pragma unroll
        for (int mt = 0; mt < 4; mt++)
#pragma unroll
            for (int nt = 0; nt < 2; nt++)
                acc[mt][nt] = __builtin_amdgcn_mfma_f32_16x16x32_bf16(a[mt], bfr[nt], acc[mt][nt], 0, 0, 0);
    }

    __syncthreads();
#pragma unroll
    for (int mt = 0; mt < 4; mt++)
#pragma unroll
        for (int i = 0; i < 4; i++) {
            int rl = mt * 16 + quad * 4 + i;
#pragma unroll
            for (int nt = 0; nt < 2; nt++)
                As[rl * KP + wcol + nt * 16 + l16] = f2bf(acc[mt][nt][i]);
        }
    __syncthreads();
#pragma unroll
    for (int it = 0; it < 4; it++) {
        int idx = tid + it * 256;
        int r = idx >> 4, c8 = idx & 15;
        if (row0 + r <= M)                             // <= M: row M = zero pad row
            *(uint4*)(C + (size_t)(row0 + r) * 256 + col0 + c8 * 8) =
                *(const uint4*)(As + r * KP + c8 * 8);
    }
}

// ---------------- build v4: HALF-bucket blocks for occupancy ----------------
// 2 blocks per bucket, each owning 256 nodes: 392 blocks x 33.8 KB LDS -> 4 blocks/CU
// fit, all CUs busy (vs 196 blocks x 66 KB = 1/CU on 196 CUs at 25% occupancy).
// Each block scans its bucket's full segment, places only its half (edge placed once).
__global__ __launch_bounds__(512) void build_csr4(const uint2* __restrict__ pairs,
                                                  const int* __restrict__ cursor,
                                                  float* __restrict__ invd,
                                                  int* __restrict__ colsF,
                                                  uint2* __restrict__ pool,
                                                  int* __restrict__ gcnt,
                                                  int Nn) {
    __shared__ int s_fix[256 * 32];                    // 32 KB fixed table (half bucket)
    __shared__ int s_cnt[256];
    const int tid = threadIdx.x;
    const int b = blockIdx.x >> 1;                     // bucket
    const int d0 = b * 512 + (blockIdx.x & 1) * 256;   // this block's first node
    if (d0 >= Nn) return;                              // uniform early-out (tail bucket halves)
    const int nd = min(256, Nn - d0);
    const size_t base = (size_t)b * BUCKCAP;
    const int n = min(cursor[b], BUCKCAP);
    if (tid < 256) s_cnt[tid] = 0;
    __syncthreads();
    for (int k = tid; k < n; k += 512) {               // scan full bucket, place own half only
        uint2 pr = pairs[base + k];
        u32 dl = pr.x - (u32)d0;
        if (dl < 256u) {
            int p = atomicAdd(&s_cnt[dl], 1);
            if (p < 32) s_fix[dl * 32 + p] = (int)pr.y;
            else {
                int q = atomicAdd(gcnt, 1);
                if (q < POOLCAP) pool[q] = make_uint2(pr.x, pr.y);
            }
        }
    }
    __syncthreads();
    if (tid < nd) invd[d0 + tid] = 1.0f / (float)max(s_cnt[tid], 1);
    // coalesced writeback; sentinels + deg tag synthesized on the fly
    int4* dst4 = (int4*)(colsF + (size_t)d0 * 32);
    for (int k = tid; k < 256 * 32 / 4; k += 512) {
        int node = k >> 3;                             // 8 int4 per node
        int cnt = s_cnt[node];
        int dg = min(cnt, 0x7fff) << 17;
        int sb = (k & 7) * 4;
        int4 v;
        v.x = ((sb + 0 < cnt) ? s_fix[k * 4 + 0] : Nn) | dg;
        v.y = ((sb + 1 < cnt) ? s_fix[k * 4 + 1] : Nn) | dg;
        v.z = ((sb + 2 < cnt) ? s_fix[k * 4 + 2] : Nn) | dg;
        v.w = ((sb + 3 < cnt) ? s_fix[k * 4 + 3] : Nn) | dg;
        dst4[k] = v;
    }
}

// ---------------- standalone GEMM (layers 1-2): C[M][NCOLS] = A[M][128] @ Bt^T ----------------
template <int NCOLS, bool AF32>
__global__ __launch_bounds__(256) void gemm_bf16(const void* __restrict__ Ap,
                                                 const u16* __restrict__ Bt,
                                                 u16* __restrict__ C, int M) {
    __shared__ u16 As[64 * KP];
    __shared__ u16 Bs[128 * KP];
    const int row0 = blockIdx.x * 64;
    const int col0 = blockIdx.y * 128;
    const int tid = threadIdx.x;

#pragma unroll
    for (int i = 0; i < 4; i++) {
        int idx = tid + i * 256;
        int r = idx >> 4, c = idx & 15;
        uint4 v = make_uint4(0, 0, 0, 0);
        if (row0 + r < M) {
            if (AF32) {
                const float* Af = (const float*)Ap;
                const float4* rowp = (const float4*)(Af + (size_t)(row0 + r) * KDIM);
                float4 f0 = rowp[2 * c];
                float4 f1 = rowp[2 * c + 1];
                v.x = (u32)f2bf(f0.x) | ((u32)f2bf(f0.y) << 16);
                v.y = (u32)f2bf(f0.z) | ((u32)f2bf(f0.w) << 16);
                v.z = (u32)f2bf(f1.x) | ((u32)f2bf(f1.y) << 16);
                v.w = (u32)f2bf(f1.z) | ((u32)f2bf(f1.w) << 16);
            } else {
                const u16* Ab = (const u16*)Ap;
                v = ((const uint4*)(Ab + (size_t)(row0 + r) * KDIM))[c];
            }
        }
        ((uint4*)(As + r * KP))[c] = v;
    }
#pragma unroll
    for (int i = 0; i < 8; i++) {
        int idx = tid + i * 256;
        int r = idx >> 4, c = idx & 15;
        uint4 v = ((const uint4*)(Bt + (size_t)(col0 + r) * KDIM))[c];
        ((uint4*)(Bs + r * KP))[c] = v;
    }
    __syncthreads();

    const int lane = tid & 63, wave = tid >> 6;
    const int quad = lane >> 4, l16 = lane & 15;
    const int wcol = wave * 32;

    f32x4 acc[4][2];
#pragma unroll
    for (int mt = 0; mt < 4; mt++)
#pragma unroll
        for (int nt = 0; nt < 2; nt++) acc[mt][nt] = (f32x4){0.f, 0.f, 0.f, 0.f};

#pragma unroll
    for (int kc = 0; kc < 4; kc++) {
        short8 a[4], b[2];
#pragma unroll
        for (int mt = 0; mt < 4; mt++)
            a[mt] = *(const short8*)(As + (size_t)(mt * 16 + l16) * KP + kc * 32 + quad * 8);
#pragma unroll
        for (int nt = 0; nt < 2; nt++)
            b[nt] = *(const short8*)(Bs + (size_t)(wcol + nt * 16 + l16) * KP + kc * 32 + quad * 8);
#pragma unroll
        for (int mt = 0; mt < 4; mt++)
#pragma unroll
            for (int nt = 0; nt < 2; nt++)
                acc[mt][nt] = __builtin_amdgcn_mfma_f32_16x16x32_bf16(a[mt], b[nt], acc[mt][nt], 0, 0, 0);
    }

    __syncthreads();
#pragma unroll
    for (int mt = 0; mt < 4; mt++)
#pragma unroll
        for (int i = 0; i < 4; i++) {
            int rl = mt * 16 + quad * 4 + i;
#pragma unroll
            for (int nt = 0; nt < 2; nt++)
                As[rl * KP + wcol + nt * 16 + l16] = f2bf(acc[mt][nt][i]);
        }
    __syncthreads();
#pragma unroll
    for (int it = 0; it < 4; it++) {
        int idx = tid + it * 256;
        int r = idx >> 4, c8 = idx & 15;
        if (row0 + r <= M)                             // <= M: row M = zero pad row
            *(uint4*)(C + (size_t)(row0 + r) * NCOLS + col0 + c8 * 8) =
                *(const uint4*)(As + r * KP + c8 * 8);
    }
}

// ---------------- 128-col aggregation, fixed-stride + scalar deg-gating + in-kernel overflow ----------------
template <bool RELU>
__global__ __launch_bounds__(256) void agg128f_k(const u16* __restrict__ out2,
                                                 const int* __restrict__ colsF,
                                                 const float* __restrict__ invd,
                                                 const float* __restrict__ bias,
                                                 const uint2* __restrict__ pool,
                                                 const int* __restrict__ gcnt,
                                                 u16* __restrict__ outp, int Mn) {
    int wave = threadIdx.x >> 6, lane = threadIdx.x & 63;
    int node = blockIdx.x * 4 + wave;
    if (node >= Mn) return;
    int sub = lane >> 4, l16 = lane & 15;
    const u16* tb = out2 + 128 + 8 * l16;
    const int* cp = colsF + node * 32 + sub;
    int s0 = cp[0],  s1 = cp[4],  s2 = cp[8],  s3 = cp[12];
    int s4 = cp[16], s5 = cp[20], s6 = cp[24], s7 = cp[28];
    const int deg = __builtin_amdgcn_readfirstlane(s0 >> 17);   // wave-uniform degree -> SGPR
    s0 &= IDXMASK; s1 &= IDXMASK; s2 &= IDXMASK; s3 &= IDXMASK;
    s4 &= IDXMASK; s5 &= IDXMASK; s6 &= IDXMASK; s7 &= IDXMASK;
    float id = invd[node];
    uint4 sv = *(const uint4*)(out2 + (size_t)node * 256 + 8 * l16);
    float4 b0 = *(const float4*)(bias + 8 * l16);
    float4 b1 = *(const float4*)(bias + 8 * l16 + 4);
    uint4 v0 = *(const uint4*)(tb + (size_t)s0 * 256);
    uint4 v1 = *(const uint4*)(tb + (size_t)s1 * 256);
    uint4 v2 = *(const uint4*)(tb + (size_t)s2 * 256);
    uint4 v3 = *(const uint4*)(tb + (size_t)s3 * 256);
    uint4 v4 = *(const uint4*)(tb + (size_t)s4 * 256);
    uint4 v5 = *(const uint4*)(tb + (size_t)s5 * 256);
    uint4 v6 = *(const uint4*)(tb + (size_t)s6 * 256);
    uint4 v7 = *(const uint4*)(tb + (size_t)s7 * 256);
    float2 a[4];
#pragma unroll
    for (int i = 0; i < 4; i++) a[i] = make_float2(0.f, 0.f);
    acc_u4p(a, v0);
    if (deg > 4)  acc_u4p(a, v1);
    if (deg > 8)  acc_u4p(a, v2);
    if (deg > 12) acc_u4p(a, v3);
    if (deg > 16) {
        acc_u4p(a, v4);
        if (deg > 20) acc_u4p(a, v5);
        if (deg > 24) acc_u4p(a, v6);
        if (deg > 28) acc_u4p(a, v7);
    }
    if (deg > 32) {                                    // in-kernel overflow (rare, scalar branch)
        int cnt = min(*gcnt, POOLCAP);
        for (int j = 0; j < cnt; j++) {
            uint2 pe = pool[j];
            if ((int)pe.x == node && sub == (j & 3))
                acc_u4p(a, *(const uint4*)(tb + (size_t)pe.y * 256));
        }
    }
    float af[8] = {a[0].x, a[0].y, a[1].x, a[1].y, a[2].x, a[2].y, a[3].x, a[3].y};
#pragma unroll
    for (int j = 0; j < 8; j++) {
        af[j] += __shfl_xor(af[j], 16); af[j] += __shfl_xor(af[j], 32);
    }
    if (sub == 0) {
        float o0 = bf2f(sv.x & 0xffffu) + af[0] * id + b0.x;
        float o1 = bf2f(sv.x >> 16)     + af[1] * id + b0.y;
        float o2 = bf2f(sv.y & 0xffffu) + af[2] * id + b0.z;
        float o3 = bf2f(sv.y >> 16)     + af[3] * id + b0.w;
        float o4 = bf2f(sv.z & 0xffffu) + af[4] * id + b1.x;
        float o5 = bf2f(sv.z >> 16)     + af[5] * id + b1.y;
        float o6 = bf2f(sv.w & 0xffffu) + af[6] * id + b1.z;
        float o7 = bf2f(sv.w >> 16)     + af[7] * id + b1.w;
        if (RELU) {
            o0 = fmaxf(o0, 0.f); o1 = fmaxf(o1, 0.f); o2 = fmaxf(o2, 0.f); o3 = fmaxf(o3, 0.f);
            o4 = fmaxf(o4, 0.f); o5 = fmaxf(o5, 0.f); o6 = fmaxf(o6, 0.f); o7 = fmaxf(o7, 0.f);
        }
        uint4 w;
        w.x = (u32)f2bf(o0) | ((u32)f2bf(o1) << 16);
        w.y = (u32)f2bf(o2) | ((u32)f2bf(o3) << 16);
        w.z = (u32)f2bf(o4) | ((u32)f2bf(o5) << 16);
        w.w = (u32)f2bf(o6) | ((u32)f2bf(o7) << 16);
        *(uint4*)(outp + (size_t)node * 128 + 8 * l16) = w;
    }
}

// ---------------- layer-2 aggregation, fixed-stride + scalar deg-gating + in-kernel overflow ----------------
__global__ __launch_bounds__(256) void agg_out8f_k(const u16* __restrict__ out2,
                                                   const int* __restrict__ colsF,
                                                   const float* __restrict__ invd,
                                                   const float* __restrict__ bias,
                                                   const uint2* __restrict__ pool,
                                                   const int* __restrict__ gcnt,
                                                   float* __restrict__ outp, int Mn) {
    int wave = threadIdx.x >> 6, lane = threadIdx.x & 63;
    int node = blockIdx.x * 4 + wave;
    if (node >= Mn) return;
    int e8 = lane >> 3, l8 = lane & 7;
    const u16* tb = out2 + 64 + 8 * l8;
    const int* cp = colsF + node * 32 + e8;
    int s0 = cp[0], s1 = cp[8], s2 = cp[16], s3 = cp[24];
    const int deg = __builtin_amdgcn_readfirstlane(s0 >> 17);
    s0 &= IDXMASK; s1 &= IDXMASK; s2 &= IDXMASK; s3 &= IDXMASK;
    float id = invd[node];
    uint4 sv = *(const uint4*)(out2 + (size_t)node * 128 + 8 * l8);
    uint4 v0 = *(const uint4*)(tb + (size_t)s0 * 128);
    uint4 v1 = *(const uint4*)(tb + (size_t)s1 * 128);
    uint4 v2 = *(const uint4*)(tb + (size_t)s2 * 128);
    uint4 v3 = *(const uint4*)(tb + (size_t)s3 * 128);
    float2 a[4];
#pragma unroll
    for (int i = 0; i < 4; i++) a[i] = make_float2(0.f, 0.f);
    acc_u4p(a, v0);
    if (deg > 8)  acc_u4p(a, v1);
    if (deg > 16) acc_u4p(a, v2);
    if (deg > 24) acc_u4p(a, v3);
    if (deg > 32) {                                    // in-kernel overflow (rare)
        int cnt = min(*gcnt, POOLCAP);
        for (int j = 0; j < cnt; j++) {
            uint2 pe = pool[j];
            if ((int)pe.x == node && e8 == (j & 7))
                acc_u4p(a, *(const uint4*)(tb + (size_t)pe.y * 128));
        }
    }
    float af[8] = {a[0].x, a[0].y, a[1].x, a[1].y, a[2].x, a[2].y, a[3].x, a[3].y};
#pragma unroll
    for (int j = 0; j < 8; j++) {
        af[j] += __shfl_xor(af[j], 8); af[j] += __shfl_xor(af[j], 16); af[j] += __shfl_xor(af[j], 32);
    }
    if (e8 == 0) {
        u32 sw[4] = {sv.x, sv.y, sv.z, sv.w};
        float* orow = outp + (size_t)node * 47;
#pragma unroll
        for (int j = 0; j < 8; j++) {
            int c = 8 * l8 + j;
            if (c < 47) {
                float s = bf2f((j & 1) ? (sw[j >> 1] >> 16) : (sw[j >> 1] & 0xffffu));
                orow[c] = s + af[j] * id + bias[c];
            }
        }
    }
}

// ---------------- launch ----------------

extern "C" void kernel_launch(void* const* d_in, const int* in_sizes, int n_in,
                              void* d_out, int out_size, void* d_ws, size_t ws_size,
                              hipStream_t stream) {
    const float* x   = (const float*)d_in[0];
    const int*   src = (const int*)d_in[1];
    const int*   dst = (const int*)d_in[2];
    const float* ws0 = (const float*)d_in[3];
    const float* wn0 = (const float*)d_in[4];
    const float* b0  = (const float*)d_in[5];
    const float* ws1 = (const float*)d_in[6];
    const float* wn1 = (const float*)d_in[7];
    const float* b1  = (const float*)d_in[8];
    const float* ws2 = (const float*)d_in[9];
    const float* wn2 = (const float*)d_in[10];
    const float* b2  = (const float*)d_in[11];

    const int Nn = in_sizes[0] / 128;   // 100000
    const int E  = in_sizes[1];         // 1600000
    const int nBuckets = (Nn + 511) / 512;
    const int NnPad = nBuckets * 512;
    const int nRowTiles = (Nn + 63) / 64;
    const int NS = (E + TILE - 1) / TILE;              // scatter blocks

    char* p = (char*)d_ws;
    auto alloc = [&](size_t bytes) -> void* {
        void* r = (void*)p;
        p += (bytes + 255) & ~(size_t)255;
        return r;
    };
    u16*   bufA   = (u16*)alloc((size_t)Nn * 128 * 2);            // h1 / h2; pairs overlay (dead until agg0)
    u16*   out2   = (u16*)alloc(((size_t)Nn * 256 + 256) * 2);    // [s|t] per layer + zero pad row
    u16*   wt0    = (u16*)alloc(256 * 128 * 2);
    u16*   wt1    = (u16*)alloc(256 * 128 * 2);
    u16*   wt2    = (u16*)alloc(128 * 128 * 2);
    float* invd   = (float*)alloc((size_t)Nn * 4);
    int*   colsF  = (int*)alloc((size_t)NnPad * 32 * 4);          // fixed-stride edge table (deg<<17|src)
    uint2* pool   = (uint2*)alloc((size_t)POOLCAP * 8);           // deg>32 overflow
    int*   ctrl   = (int*)alloc(257 * 4);                         // cursor[256] + gcnt
    int*   cursor = ctrl;
    int*   gcnt   = ctrl + 256;
    uint2* pairs  = (uint2*)bufA;                                 // 256*BUCKCAP*8 = 25.17 MB <= bufA 25.6 MB

    // 1: weight transpose + ctrl zero
    prep_ctrl<<<161, 512, 0, stream>>>(ws0, wn0, wt0, ws1, wn1, wt1, ws2, wn2, wt2, ctrl);
    // 2: lean scatter CONCURRENT with gemm layer 0
    scatter_gemm0<<<NS + nRowTiles * 2, 256, 0, stream>>>(src, dst, cursor, pairs, E, NS,
                                                          x, wt0, out2, Nn, nRowTiles);
    // 3: fixed-stride table build (half-bucket blocks for occupancy)
    build_csr4<<<nBuckets * 2, 512, 0, stream>>>(pairs, cursor, invd, colsF, pool, gcnt, Nn);

    dim3 ggrid(nRowTiles, 2);
    dim3 ggrid1(nRowTiles, 1);
    const int aggGrid = (Nn + 3) / 4;                    // 4 waves x 1 node
    // 4: layer 0 aggregation (writes bufA, clobbering consumed pairs)
    agg128f_k<true><<<aggGrid, 256, 0, stream>>>(out2, colsF, invd, b0, pool, gcnt, bufA, Nn);
    // 5-6: layer 1
    gemm_bf16<256, false><<<ggrid, 256, 0, stream>>>(bufA, wt1, out2, Nn);
    agg128f_k<true><<<aggGrid, 256, 0, stream>>>(out2, colsF, invd, b1, pool, gcnt, bufA, Nn);
    // 7-8: layer 2
    gemm_bf16<128, false><<<ggrid1, 256, 0, stream>>>(bufA, wt2, out2, Nn);
    agg_out8f_k<<<aggGrid, 256, 0, stream>>>(out2, colsF, invd, b2, pool, gcnt, (float*)d_out, Nn);
}